// Round 21
// baseline (149.623 us; speedup 1.0000x reference)
//
#include <hip/hip_runtime.h>
#include <hip/hip_bf16.h>
#include <hip/hip_fp16.h>
#include <stdint.h>

#define BSZ 32
#define SEQ 512
#define EMB 512
#define NH  8
#define DKD 64
#define LOG2E 1.4426950408889634f

typedef float f32x4 __attribute__((ext_vector_type(4)));
typedef short s16x8 __attribute__((ext_vector_type(8)));

#if __has_builtin(__builtin_amdgcn_exp2f)
#define EXP2(x) __builtin_amdgcn_exp2f(x)
#else
#define EXP2(x) exp2f(x)
#endif
#define RCP(x) __builtin_amdgcn_rcpf(x)

__device__ inline unsigned short f2bf(float f) {
  union { float f; unsigned u; } v; v.f = f;
  unsigned r = v.u + 0x7fffu + ((v.u >> 16) & 1u);   // RNE
  return (unsigned short)(r >> 16);
}

__device__ inline ushort4 pack4bf(float4 v) {
  union { __hip_bfloat162 h2[2]; ushort4 u4; } cv;
  cv.h2[0] = __float22bfloat162_rn(make_float2(v.x, v.y));
  cv.h2[1] = __float22bfloat162_rn(make_float2(v.z, v.w));
  return cv.u4;
}

// async global->LDS, 16 B per lane. LDS dest must be wave-uniform base + lane*16.
__device__ inline void stage16(const void* g, void* l) {
#if defined(__has_builtin) && __has_builtin(__builtin_amdgcn_global_load_lds)
  __builtin_amdgcn_global_load_lds(
      (const __attribute__((address_space(1))) void*)g,
      (__attribute__((address_space(3))) void*)l, 16, 0, 0);
#else
  *reinterpret_cast<uint4*>(l) = *reinterpret_cast<const uint4*>(g);
#endif
}

template<int CTRL>
__device__ inline float dpp_shr_f(float x) {
  return __builtin_bit_cast(float,
    __builtin_amdgcn_update_dpp(0, __builtin_bit_cast(int, x), CTRL, 0xf, 0xf, true));
}
__device__ inline float rlane(float v, int l) {
  return __builtin_bit_cast(float, __builtin_amdgcn_readlane(__builtin_bit_cast(int, v), l));
}

// Convert 4 weight matrices (EMB*EMB f32) to bf16. grid (128, 4).
__global__ __launch_bounds__(256)
void wcvt(const float* __restrict__ w0, const float* __restrict__ w1,
          const float* __restrict__ w2, const float* __restrict__ w3,
          unsigned short* __restrict__ o0, unsigned short* __restrict__ o1,
          unsigned short* __restrict__ o2, unsigned short* __restrict__ o3)
{
  const float* src = (blockIdx.y == 0) ? w0 : (blockIdx.y == 1) ? w1
                   : (blockIdx.y == 2) ? w2 : w3;
  unsigned short* dst = (blockIdx.y == 0) ? o0 : (blockIdx.y == 1) ? o1
                      : (blockIdx.y == 2) ? o2 : o3;
  const int i = (blockIdx.x * 256 + threadIdx.x) * 8;
  float4 a = *reinterpret_cast<const float4*>(src + i);
  float4 b = *reinterpret_cast<const float4*>(src + i + 4);
  union { ushort4 p[2]; s16x8 v; } cc;
  cc.p[0] = pack4bf(a); cc.p[1] = pack4bf(b);
  *reinterpret_cast<s16x8*>(dst + i) = cc.v;
}

// ============ fused projection GEMM (q,k,v) — phase-major decode ===========
// Grid 3072. phase = lin>>10 selects the projection; within a phase the
// decode is BIT-IDENTICAL to the R15 standalone kernel: x = lin&7;
// u = (lin&1023)>>3; panel = x*32 + (u&31) (pinned per CU); nb = u>>5.
// Per-CU / per-XCD working sets stay SINGLE-projection (4 MB = L2-fit).
// Inner loop: counted-vmcnt double-buffer (4 stage16/thread/step).
// Epilogue: LDS-staged coalesced 16B stores.
// phase 0: Qh [b,h,s,d] (scaled); 1: Kh [b,h,s,d]; 2: Vt [b,h,d,s].
// Locked config: best measured total (148.6/149.7/149.3 us, R16/R18/R20).
__global__ __launch_bounds__(256)
void proj_gemm(const float* __restrict__ q, const float* __restrict__ k,
               const float* __restrict__ v,
               const unsigned short* __restrict__ Wq,
               const unsigned short* __restrict__ Wk,
               const unsigned short* __restrict__ Wv,
               const float* __restrict__ bq, const float* __restrict__ bk,
               const float* __restrict__ bv,
               unsigned short* __restrict__ Qh, unsigned short* __restrict__ Kh,
               unsigned short* __restrict__ Vt, float qscale)
{
  __shared__ __align__(16) char smem[2 * 16384];
  const int tid  = threadIdx.x;
  const int lane = tid & 63;
  const int w    = tid >> 6;
  const int lin  = blockIdx.x;
  const int proj = lin >> 10;
  const int x    = lin & 7;
  const int u    = (lin & 1023) >> 3;
  const int panel= x * 32 + (u & 31);
  const int nb   = u >> 5;
  const int m0   = panel * 64;
  const int n0   = nb * 128;
  const int K = EMB;
  const float* A = (proj == 0) ? q : (proj == 1) ? k : v;
  const unsigned short* Bw = (proj == 0) ? Wq : (proj == 1) ? Wk : Wv;
  const float* bias = (proj == 0) ? bq : (proj == 1) ? bk : bv;
  unsigned short* Out = (proj == 0) ? Qh : (proj == 1) ? Kh : Vt;
  const float oscale = (proj == 0) ? qscale : 1.0f;

  const int wr   = (w >> 1) * 32;     // 0 or 32
  const int wc   = (w & 1) * 64;      // 0 or 64
  const int base = w * 1024 + lane * 16;

  auto stage = [&](int buf, int k0) {   // exactly 4 stage16 per thread
    char* sA = smem + buf * 16384;
    char* sB = sA + 8192;
    #pragma unroll
    for (int c = 0; c < 2; ++c) {       // A: 8 KB f32 [64 rows][8 granules of 4 f32]
      const int flat = c * 4096 + base;
      const int row  = flat >> 7;
      const int gl   = ((flat >> 4) & 7) ^ (row & 7);
      stage16(&A[(size_t)(m0 + row) * K + k0 + gl * 4], sA + flat);
    }
    #pragma unroll
    for (int c = 0; c < 2; ++c) {       // B: 8 KB bf16, 128 n-rows x 32 cols
      const int flat = c * 4096 + base;
      const int r    = flat >> 7;
      const int gl   = ((flat >> 4) & 7) ^ (r & 7);
      const int nn   = r + ((gl >> 2) << 6);
      stage16(&Bw[(size_t)(n0 + nn) * K + k0 + (gl & 3) * 8], sB + flat);
    }
  };

  f32x4 acc[2][4] = {};
  auto compute = [&](int buf) {
    char* sA = smem + buf * 16384;
    char* sB = sA + 8192;
    s16x8 af[2], bf[4];
    #pragma unroll
    for (int i = 0; i < 2; ++i) {
      const int row = wr + i * 16 + (lane & 15);
      const int g1  = (lane >> 4) << 1;
      float4 v1 = *reinterpret_cast<const float4*>(sA + row * 128 + ((g1 ^ (row & 7)) << 4));
      float4 v2 = *reinterpret_cast<const float4*>(sA + row * 128 + (((g1 + 1) ^ (row & 7)) << 4));
      union { ushort4 p[2]; s16x8 vv; } cc;
      cc.p[0] = pack4bf(v1); cc.p[1] = pack4bf(v2);
      af[i] = cc.vv;
    }
    #pragma unroll
    for (int jj = 0; jj < 4; ++jj) {
      const int n  = wc + jj * 16 + (lane & 15);
      const int r  = n & 63;
      const int gl = ((n >> 6) << 2) + (lane >> 4);
      bf[jj] = *reinterpret_cast<const s16x8*>(sB + r * 128 + ((gl ^ (r & 7)) << 4));
    }
    __builtin_amdgcn_s_setprio(1);
    #pragma unroll
    for (int i = 0; i < 2; ++i)
      #pragma unroll
      for (int jj = 0; jj < 4; ++jj)
        acc[i][jj] = __builtin_amdgcn_mfma_f32_16x16x32_bf16(af[i], bf[jj], acc[i][jj], 0, 0, 0);
    __builtin_amdgcn_s_setprio(0);
  };

  stage(0, 0);
  int cur = 0;
  for (int t = 0; t < 15; ++t) {
    stage(cur ^ 1, (t + 1) * 32);       // stays in flight across the barrier
    asm volatile("s_waitcnt vmcnt(4)" ::: "memory");   // tile t landed
    __builtin_amdgcn_s_barrier();
    __builtin_amdgcn_sched_barrier(0);
    compute(cur);
    asm volatile("s_waitcnt lgkmcnt(0)" ::: "memory"); // ds_reads done
    __builtin_amdgcn_s_barrier();
    cur ^= 1;
  }
  asm volatile("s_waitcnt vmcnt(0)" ::: "memory");
  __builtin_amdgcn_s_barrier();
  __builtin_amdgcn_sched_barrier(0);
  compute(cur);
  __syncthreads();                      // smem reused by epilogue tile

  // ---- epilogue: bf16 tile through LDS, then coalesced 16B stores ----
  // proj 0/1: tile [64 m][256 B of n];  proj 2: tile [128 n][128 B of m].
  char* const tl = smem;
  #pragma unroll
  for (int jj = 0; jj < 4; ++jj) {
    const int n  = wc + jj * 16 + (lane & 15);
    const float bs = bias[n0 + n];
    #pragma unroll
    for (int i = 0; i < 2; ++i)
      #pragma unroll
      for (int r = 0; r < 4; ++r) {
        const int m = wr + i * 16 + (lane >> 4) * 4 + r;
        const unsigned short val = f2bf((acc[i][jj][r] + bs) * oscale);
        if (proj == 2)
          *(unsigned short*)(tl + n * 128 + ((m * 2) ^ ((n & 7) << 4))) = val;
        else
          *(unsigned short*)(tl + m * 256 + ((n * 2) ^ ((m & 7) << 4))) = val;
      }
  }
  __syncthreads();
  #pragma unroll
  for (int c = 0; c < 4; ++c) {
    const int flat = c * 4096 + tid * 16;
    size_t dst;
    s16x8 vchunk;
    if (proj == 2) {
      const int rowi = flat >> 7;           // n: 0..127
      const int cb   = flat & 127;          // m-bytes
      vchunk = *reinterpret_cast<const s16x8*>(tl + rowi * 128 + (cb ^ ((rowi & 7) << 4)));
      const int gn = n0 + rowi;
      const int b  = m0 >> 9, sb = (m0 & 511) + (cb >> 1);
      const int h  = gn >> 6, d = gn & 63;
      dst = ((size_t)(b * NH + h) * DKD + d) * SEQ + sb;
    } else {
      const int rowi = flat >> 8;           // m: 0..63
      const int cb   = flat & 255;          // n-bytes
      vchunk = *reinterpret_cast<const s16x8*>(tl + rowi * 256 + (cb ^ ((rowi & 7) << 4)));
      const int gm = m0 + rowi;
      const int gn = n0 + (cb >> 1);
      const int b  = gm >> 9, s = gm & 511;
      const int h  = gn >> 6, d = gn & 63;
      dst = ((size_t)(b * NH + h) * SEQ + s) * DKD + d;
    }
    *reinterpret_cast<s16x8*>(&Out[dst]) = vchunk;
  }
}

// ===================== output GEMM (At bf16 @ Wo^T + bo -> f32) ============
// Grid 512 1-D, XCD-pinned (P = x*16 + (j>>2): b in [4x,4x+4) matches attn's
// producer XCD). Counted-vmcnt dbuf pipeline; 4 loads/thread -> vmcnt(4).
__global__ __launch_bounds__(256)
void out_gemm(const unsigned short* __restrict__ At,
              const unsigned short* __restrict__ Wo,
              const float* __restrict__ bo, float* __restrict__ C)
{
  __shared__ __align__(16) char smem[2 * 16384];
  const int tid  = threadIdx.x;
  const int lane = tid & 63;
  const int w    = tid >> 6;
  const int lin  = blockIdx.x;
  const int x    = lin & 7;
  const int j    = lin >> 3;
  const int P    = x * 16 + (j >> 2);
  const int m0   = P * 128;
  const int n0   = (j & 3) * 128;
  const int K = EMB, N = EMB;

  const int wr   = (w >> 1) * 64;
  const int wc   = (w & 1) * 64;
  const int base = w * 1024 + lane * 16;

  auto stage = [&](int buf, int k0) {   // exactly 4 global_load_lds per thread
    char* sA = smem + buf * 16384;
    char* sB = sA + 8192;
    #pragma unroll
    for (int c = 0; c < 2; ++c) {
      const int flat = c * 4096 + base;
      const int r    = flat >> 7;
      const int gl   = ((flat >> 4) & 7) ^ (r & 7);
      const int row  = r + ((gl >> 2) << 6);
      stage16(&At[(size_t)(m0 + row) * K + k0 + (gl & 3) * 8], sA + flat);
    }
    #pragma unroll
    for (int c = 0; c < 2; ++c) {
      const int flat = c * 4096 + base;
      const int r    = flat >> 7;
      const int gl   = ((flat >> 4) & 7) ^ (r & 7);
      const int nn   = r + ((gl >> 2) << 6);
      stage16(&Wo[(size_t)(n0 + nn) * K + k0 + (gl & 3) * 8], sB + flat);
    }
  };

  f32x4 acc[4][4] = {};
  auto compute = [&](int buf) {
    char* sA = smem + buf * 16384;
    char* sB = sA + 8192;
    s16x8 af[4], bf[4];
    #pragma unroll
    for (int i = 0; i < 4; ++i) {
      const int row = wr + i * 16 + (lane & 15);
      const int r   = row & 63;
      const int gl  = ((row >> 6) << 2) + (lane >> 4);
      af[i] = *reinterpret_cast<const s16x8*>(sA + r * 128 + ((gl ^ (r & 7)) << 4));
    }
    #pragma unroll
    for (int jj = 0; jj < 4; ++jj) {
      const int n  = wc + jj * 16 + (lane & 15);
      const int r  = n & 63;
      const int gl = ((n >> 6) << 2) + (lane >> 4);
      bf[jj] = *reinterpret_cast<const s16x8*>(sB + r * 128 + ((gl ^ (r & 7)) << 4));
    }
    __builtin_amdgcn_s_setprio(1);
    #pragma unroll
    for (int i = 0; i < 4; ++i)
      #pragma unroll
      for (int jj = 0; jj < 4; ++jj)
        acc[i][jj] = __builtin_amdgcn_mfma_f32_16x16x32_bf16(af[i], bf[jj], acc[i][jj], 0, 0, 0);
    __builtin_amdgcn_s_setprio(0);
  };

  stage(0, 0);
  int cur = 0;
  for (int t = 0; t < 15; ++t) {
    stage(cur ^ 1, (t + 1) * 32);
    asm volatile("s_waitcnt vmcnt(4)" ::: "memory");
    __builtin_amdgcn_s_barrier();
    __builtin_amdgcn_sched_barrier(0);
    compute(cur);
    asm volatile("s_waitcnt lgkmcnt(0)" ::: "memory");
    __builtin_amdgcn_s_barrier();
    cur ^= 1;
  }
  asm volatile("s_waitcnt vmcnt(0)" ::: "memory");
  __builtin_amdgcn_s_barrier();
  __builtin_amdgcn_sched_barrier(0);
  compute(cur);

  #pragma unroll
  for (int i = 0; i < 4; ++i)
    #pragma unroll
    for (int jj = 0; jj < 4; ++jj)
      #pragma unroll
      for (int r = 0; r < 4; ++r) {
        const int gm = m0 + wr + i * 16 + (lane >> 4) * 4 + r;
        const int gn = n0 + wc + jj * 16 + (lane & 15);
        C[(size_t)gm * N + gn] = acc[i][jj][r] + bo[gn];
      }
}

// ---- phase 2 worker: R rows per iteration, 64/R lanes per row segment.
// R21 change: DEFERRED NORMALIZATION. P is stored as RAW p2 (bf16); the
// per-row 1/sum factor inv2 goes to inv2v[16] in LDS and is applied once to
// the f32 accumulator in phase 3's epilogue (out[q,*] = inv2_q * sum p2*V).
// Saves ~8 mul + reg copy per row in the issue-bound hot loop; bf16 relative
// rounding is scale-invariant so error is unchanged to first order.
template<int R>
__device__ inline void phase2_rows(unsigned short* s_lds, float* inv2v,
                                   int w, int lane, int q0, int zp, float g2)
{
  constexpr int L  = 64 / R;   // lanes per segment
  constexpr int IT = 4 / R;    // iterations
  const int seg = lane / L;
  const int li  = lane & (L - 1);
  const int jb  = li * 8;
  const float NEGINF = -__builtin_inff();
  #pragma unroll
  for (int it = 0; it < IT; ++it) {
    const int r  = w * 4 + it * R + seg;
    const int qg = q0 + r;
    const int gs = li ^ (r & 7);
    unsigned short* rowp = &s_lds[r * 512 + gs * 8];
    float p2[8];
    if (qg == 0) {
      const float u = zp ? 0.0f : (1.0f / 512.0f);
      #pragma unroll
      for (int i = 0; i < 8; ++i) p2[i] = u;
      if (li == 0) inv2v[r] = 1.0f;            // already normalized
    } else {
      float sL[8];
      {
        s16x8 raw = *reinterpret_cast<const s16x8*>(rowp);
        union { s16x8 v; __half2 h[4]; } u; u.v = raw;
        #pragma unroll
        for (int i = 0; i < 4; ++i) {
          float2 f = __half22float2(u.h[i]);
          sL[2 * i] = f.x; sL[2 * i + 1] = f.y;
        }
      }
      #pragma unroll
      for (int i = 0; i < 8; ++i) sL[i] = (jb + i < qg) ? sL[i] : NEGINF;
      float c[8];
      float run = 0.f;
      #pragma unroll
      for (int i = 0; i < 8; ++i) { const float e = EXP2(sL[i]); run += e; c[i] = run; }
      // segmented inclusive scan of per-lane totals
      float t = run;
      t += dpp_shr_f<0x111>(t);
      t += dpp_shr_f<0x112>(t);
      t += dpp_shr_f<0x114>(t);
      t += dpp_shr_f<0x118>(t);
      float tot;
      if constexpr (R == 1) {
        const float r0 = rlane(t, 15), r1 = rlane(t, 31), r2 = rlane(t, 47);
        const float a1 = r0, a2 = r0 + r1, a3 = a2 + r2;
        tot = a3 + rlane(t, 63);
        t += (lane >= 48) ? a3 : (lane >= 32) ? a2 : (lane >= 16) ? a1 : 0.f;
      } else if constexpr (R == 2) {
        const float r0 = rlane(t, 15), r2 = rlane(t, 47);
        t += (lane & 16) ? ((lane < 32) ? r0 : r2) : 0.f;
        tot = __shfl(t, lane | 31, 64);
      } else {
        tot = __shfl(t, lane | 15, 64);
      }
      const float pre  = tot - (t - run);     // tot - exclusive_prefix(lane)
      const float g2r  = g2 * __builtin_amdgcn_sqrtf(RCP(tot));
      const float fb   = (float)(qg - jb);
      float run2 = 0.f;
      #pragma unroll
      for (int i = 0; i < 8; ++i) {
        const float rem = pre - c[i];
        const float arg = fmaxf(rem * (fb - (float)i), 0.f);
        float te = EXP2(__builtin_amdgcn_sqrtf(arg) * g2r);
        te = fmaxf(te, 1e-5f);
        p2[i] = EXP2(sL[i] * te);             // RAW (unnormalized)
        run2 += p2[i];
      }
      float y = run2;
      y += dpp_shr_f<0x111>(y);
      y += dpp_shr_f<0x112>(y);
      y += dpp_shr_f<0x114>(y);
      y += dpp_shr_f<0x118>(y);
      float s2;
      if constexpr (R == 1) {
        s2 = rlane(y, 15) + rlane(y, 31) + rlane(y, 47) + rlane(y, 63);
      } else if constexpr (R == 2) {
        y += (lane & 16) ? ((lane < 32) ? rlane(y, 15) : rlane(y, 47)) : 0.f;
        s2 = __shfl(y, lane | 31, 64);
      } else {
        s2 = __shfl(y, lane | 15, 64);
      }
      if (li == 0) inv2v[r] = RCP(s2);        // normalization deferred to PV
    }
    union { __hip_bfloat162 h2[4]; uint4 u; } pk;
    pk.h2[0] = __float22bfloat162_rn(make_float2(p2[0], p2[1]));
    pk.h2[1] = __float22bfloat162_rn(make_float2(p2[2], p2[3]));
    pk.h2[2] = __float22bfloat162_rn(make_float2(p2[4], p2[5]));
    pk.h2[3] = __float22bfloat162_rn(make_float2(p2[6], p2[7]));
    *reinterpret_cast<uint4*>(rowp) = pk.u;
  }
}

// One WG (4 waves) per (b, h, 16-row q-block). Grid 8192 1-D.
// CU-pinned (b,h) decode; qb in high bits. LDS: 16 KB f16 scores,
// granule-swizzled; RAW bf16 p2 overlays the same slots; inv2v[16] carries
// per-row normalization into phase 3. Triangular trims throughout. Out: bf16.
__global__ __launch_bounds__(256)
void attn_kernel(const unsigned short* __restrict__ Qh,
                 const unsigned short* __restrict__ Kh,
                 const unsigned short* __restrict__ Vt,
                 unsigned short* __restrict__ Aout,
                 const float* __restrict__ gammas,
                 const int* __restrict__ zero_pad)
{
  __shared__ __align__(16) unsigned short s_lds[16 * 512];   // 16 KB
  __shared__ float inv2v[16];
  const int tid = threadIdx.x, lane = tid & 63, w = tid >> 6;
  const int lin = blockIdx.x;
  const int x   = lin & 7;          // xcd
  const int u   = lin >> 3;         // 0..1023 within xcd
  const int qb  = u >> 5;           // 0..31  (high bits -> varies per CU)
  const int h   = u & 7;
  const int b   = x * 4 + ((u >> 3) & 3);
  const int q0  = qb * 16;
  const size_t bh = (size_t)b * NH + h;
  const unsigned short* Qp = Qh + bh * SEQ * DKD;
  const unsigned short* Kp = Kh + bh * SEQ * DKD;
  const unsigned short* Vp = Vt + bh * DKD * SEQ;
  const int zp = zero_pad[0];
  const float g2 = -log1pf(__expf(gammas[h])) * LOG2E;  // -softplus(g) * log2(e)

  // ---- phase 1: S(log2-domain) = Qs @ K^T (Q pre-scaled by log2e/8), f16 to LDS.
  // 16-col MFMA tile t (t <= qb needed) -> wave (t & 3): balanced; 2-deep prefetch.
  s16x8 aq[2];
  #pragma unroll
  for (int kt = 0; kt < 2; ++kt)
    aq[kt] = *reinterpret_cast<const s16x8*>(&Qp[(q0 + (lane & 15)) * DKD + kt * 32 + (lane >> 4) * 8]);
  {
    const int frag = (lane >> 4) * 8;
    auto loadK = [&](int t, s16x8* kb) {
      const int n = t * 16 + (lane & 15);
      kb[0] = *reinterpret_cast<const s16x8*>(&Kp[n * DKD + frag]);
      kb[1] = *reinterpret_cast<const s16x8*>(&Kp[n * DKD + 32 + frag]);
    };
    auto tilecomp = [&](int t, const s16x8* kb) {
      f32x4 acc = {};
      __builtin_amdgcn_s_setprio(1);
      acc = __builtin_amdgcn_mfma_f32_16x16x32_bf16(aq[0], kb[0], acc, 0, 0, 0);
      acc = __builtin_amdgcn_mfma_f32_16x16x32_bf16(aq[1], kb[1], acc, 0, 0, 0);
      __builtin_amdgcn_s_setprio(0);
      const int n = t * 16 + (lane & 15);
      #pragma unroll
      for (int r = 0; r < 4; ++r) {
        const int row = (lane >> 4) * 4 + r;
        const int idx = row * 512 + ((((n >> 3) ^ (row & 7)) << 3) + (n & 7));
        s_lds[idx] = __half_as_ushort(__float2half(acc[r]));
      }
    };
    int t = w;
    if (t <= qb) {
      s16x8 cur[2], nxt[2];
      loadK(t, cur);
      while (true) {
        const int tn = t + 4;
        if (tn <= qb) {
          loadK(tn, nxt);
          tilecomp(t, cur);
          cur[0] = nxt[0]; cur[1] = nxt[1];
          t = tn;
        } else {
          tilecomp(t, cur);
          break;
        }
      }
    }
  }
  __syncthreads();

  // ---- phase 2: softmax -> cumsum -> decay -> softmax2 -> RAW bf16 p2
  if (zp == 0 && qb == 0) {
    phase2_rows<1>(s_lds, inv2v, w, lane, q0, zp, g2);   // row 0 spans all 512
  } else if (qb < 8) {
    phase2_rows<4>(s_lds, inv2v, w, lane, q0, zp, g2);
  } else if (qb < 16) {
    phase2_rows<2>(s_lds, inv2v, w, lane, q0, zp, g2);
  } else {
    phase2_rows<1>(s_lds, inv2v, w, lane, q0, zp, g2);
  }
  __syncthreads();

  // ---- phase 3: out = inv2_q * (p2 @ V) (V stored [d][s]); wave w -> d cols
  // [w*16, w*16+16). k-tile ks needed iff ks <= qb/2. Batch-4 loads.
  f32x4 oacc = {};
  const int row  = lane & 15;
  const int koff = lane >> 4;
  const int rsw  = row & 7;
  const unsigned short* vbase = &Vp[(w * 16 + row) * SEQ + koff * 8];
  const int ks_end = (qb == 0 && zp == 0) ? 16 : (qb >> 1) + 1;
  int ks0 = 0;
  for (; ks0 + 4 <= ks_end; ks0 += 4) {
    s16x8 vb[4], pa[4];
    #pragma unroll
    for (int uu = 0; uu < 4; ++uu) {
      const int ks = ks0 + uu;
      vb[uu] = *reinterpret_cast<const s16x8*>(&vbase[ks * 32]);
      pa[uu] = *reinterpret_cast<const s16x8*>(&s_lds[row * 512 + ((ks * 4 + koff) ^ rsw) * 8]);
    }
    __builtin_amdgcn_s_setprio(1);
    #pragma unroll
    for (int uu = 0; uu < 4; ++uu)
      oacc = __builtin_amdgcn_mfma_f32_16x16x32_bf16(pa[uu], vb[uu], oacc, 0, 0, 0);
    __builtin_amdgcn_s_setprio(0);
  }
  for (; ks0 < ks_end; ++ks0) {
    s16x8 vb = *reinterpret_cast<const s16x8*>(&vbase[ks0 * 32]);
    s16x8 pa = *reinterpret_cast<const s16x8*>(&s_lds[row * 512 + ((ks0 * 4 + koff) ^ rsw) * 8]);
    oacc = __builtin_amdgcn_mfma_f32_16x16x32_bf16(pa, vb, oacc, 0, 0, 0);
  }
  #pragma unroll
  for (int r = 0; r < 4; ++r) {
    const int orow = (lane >> 4) * 4 + r;
    const int ocol = w * 16 + (lane & 15);
    Aout[((size_t)b * SEQ + (q0 + orow)) * EMB + h * DKD + ocol] =
        f2bf(oacc[r] * inv2v[orow]);
  }
}

extern "C" void kernel_launch(void* const* d_in, const int* in_sizes, int n_in,
                              void* d_out, int out_size, void* d_ws, size_t ws_size,
                              hipStream_t stream)
{
  const float* q  = (const float*)d_in[0];
  const float* k  = (const float*)d_in[1];
  const float* v  = (const float*)d_in[2];
  // d_in[3] = mask (strictly causal, computed analytically on device)
  const int*   zp = (const int*)d_in[4];
  const float* Wq = (const float*)d_in[5];
  const float* bq = (const float*)d_in[6];
  const float* Wk = (const float*)d_in[7];
  const float* bk = (const float*)d_in[8];
  const float* Wv = (const float*)d_in[9];
  const float* bv = (const float*)d_in[10];
  const float* Wo = (const float*)d_in[11];
  const float* bo = (const float*)d_in[12];
  const float* gm = (const float*)d_in[13];

  char* ws = (char*)d_ws;
  const size_t HB = (size_t)BSZ * NH * SEQ * DKD * sizeof(unsigned short); // 16 MiB
  const size_t WB = (size_t)EMB * EMB * sizeof(unsigned short);            // 512 KiB
  unsigned short* Qh  = (unsigned short*)(ws);
  unsigned short* Kh  = (unsigned short*)(ws + HB);
  unsigned short* Vt  = (unsigned short*)(ws + 2 * HB);
  unsigned short* At  = (unsigned short*)(ws + 3 * HB);   // bf16 attn output
  unsigned short* Wqb = (unsigned short*)(ws + 4 * HB);
  unsigned short* Wkb = (unsigned short*)(ws + 4 * HB + WB);
  unsigned short* Wvb = (unsigned short*)(ws + 4 * HB + 2 * WB);
  unsigned short* Wob = (unsigned short*)(ws + 4 * HB + 3 * WB);

  wcvt<<<dim3(128, 4), 256, 0, stream>>>(Wq, Wk, Wv, Wo, Wqb, Wkb, Wvb, Wob);
  proj_gemm<<<3072, 256, 0, stream>>>(q, k, v, Wqb, Wkb, Wvb, bq, bk, bv,
                                      Qh, Kh, Vt, 0.125f * LOG2E);
  attn_kernel<<<8192, 256, 0, stream>>>(Qh, Kh, Vt, At, gm, zp);
  out_gemm<<<512, 256, 0, stream>>>(At, Wob, bo, (float*)d_out);
}

// Round 22
// 147.153 us; speedup vs baseline: 1.0168x; 1.0168x over previous
//
#include <hip/hip_runtime.h>
#include <hip/hip_bf16.h>
#include <hip/hip_fp16.h>
#include <stdint.h>

#define BSZ 32
#define SEQ 512
#define EMB 512
#define NH  8
#define DKD 64
#define LOG2E 1.4426950408889634f

typedef float f32x4 __attribute__((ext_vector_type(4)));
typedef short s16x8 __attribute__((ext_vector_type(8)));

#if __has_builtin(__builtin_amdgcn_exp2f)
#define EXP2(x) __builtin_amdgcn_exp2f(x)
#else
#define EXP2(x) exp2f(x)
#endif
#define RCP(x) __builtin_amdgcn_rcpf(x)

__device__ inline unsigned short f2bf(float f) {
  union { float f; unsigned u; } v; v.f = f;
  unsigned r = v.u + 0x7fffu + ((v.u >> 16) & 1u);   // RNE
  return (unsigned short)(r >> 16);
}

__device__ inline ushort4 pack4bf(float4 v) {
  union { __hip_bfloat162 h2[2]; ushort4 u4; } cv;
  cv.h2[0] = __float22bfloat162_rn(make_float2(v.x, v.y));
  cv.h2[1] = __float22bfloat162_rn(make_float2(v.z, v.w));
  return cv.u4;
}

// async global->LDS, 16 B per lane. LDS dest must be wave-uniform base + lane*16.
__device__ inline void stage16(const void* g, void* l) {
#if defined(__has_builtin) && __has_builtin(__builtin_amdgcn_global_load_lds)
  __builtin_amdgcn_global_load_lds(
      (const __attribute__((address_space(1))) void*)g,
      (__attribute__((address_space(3))) void*)l, 16, 0, 0);
#else
  *reinterpret_cast<uint4*>(l) = *reinterpret_cast<const uint4*>(g);
#endif
}

template<int CTRL>
__device__ inline float dpp_shr_f(float x) {
  return __builtin_bit_cast(float,
    __builtin_amdgcn_update_dpp(0, __builtin_bit_cast(int, x), CTRL, 0xf, 0xf, true));
}
__device__ inline float rlane(float v, int l) {
  return __builtin_bit_cast(float, __builtin_amdgcn_readlane(__builtin_bit_cast(int, v), l));
}

// Convert 4 weight matrices (EMB*EMB f32) to bf16. grid (128, 4).
__global__ __launch_bounds__(256)
void wcvt(const float* __restrict__ w0, const float* __restrict__ w1,
          const float* __restrict__ w2, const float* __restrict__ w3,
          unsigned short* __restrict__ o0, unsigned short* __restrict__ o1,
          unsigned short* __restrict__ o2, unsigned short* __restrict__ o3)
{
  const float* src = (blockIdx.y == 0) ? w0 : (blockIdx.y == 1) ? w1
                   : (blockIdx.y == 2) ? w2 : w3;
  unsigned short* dst = (blockIdx.y == 0) ? o0 : (blockIdx.y == 1) ? o1
                      : (blockIdx.y == 2) ? o2 : o3;
  const int i = (blockIdx.x * 256 + threadIdx.x) * 8;
  float4 a = *reinterpret_cast<const float4*>(src + i);
  float4 b = *reinterpret_cast<const float4*>(src + i + 4);
  union { ushort4 p[2]; s16x8 v; } cc;
  cc.p[0] = pack4bf(a); cc.p[1] = pack4bf(b);
  *reinterpret_cast<s16x8*>(dst + i) = cc.v;
}

// ============ fused projection GEMM (q,k,v) — phase-major decode ===========
// Grid 3072. phase = lin>>10 selects the projection; within a phase the
// decode: x = lin&7 (XCD); u = (lin&1023)>>3; panel = x*32 + (u&31)
// (pinned per CU); nb = u>>5. Per-CU / per-XCD working sets stay
// SINGLE-projection (4 MB = L2-fit). Counted-vmcnt double-buffer
// (4 stage16/thread/step). Epilogue: LDS-staged coalesced 16B stores.
// phase 0: Qh [b,h,s,d] (scaled); 1: Kh [b,h,s,d]; 2: Vt [b,h,d,s].
// Locked config: best measured total (148.6/149.7/149.3/149.6 us).
__global__ __launch_bounds__(256)
void proj_gemm(const float* __restrict__ q, const float* __restrict__ k,
               const float* __restrict__ v,
               const unsigned short* __restrict__ Wq,
               const unsigned short* __restrict__ Wk,
               const unsigned short* __restrict__ Wv,
               const float* __restrict__ bq, const float* __restrict__ bk,
               const float* __restrict__ bv,
               unsigned short* __restrict__ Qh, unsigned short* __restrict__ Kh,
               unsigned short* __restrict__ Vt, float qscale)
{
  __shared__ __align__(16) char smem[2 * 16384];
  const int tid  = threadIdx.x;
  const int lane = tid & 63;
  const int w    = tid >> 6;
  const int lin  = blockIdx.x;
  const int proj = lin >> 10;
  const int x    = lin & 7;
  const int u    = (lin & 1023) >> 3;
  const int panel= x * 32 + (u & 31);
  const int nb   = u >> 5;
  const int m0   = panel * 64;
  const int n0   = nb * 128;
  const int K = EMB;
  const float* A = (proj == 0) ? q : (proj == 1) ? k : v;
  const unsigned short* Bw = (proj == 0) ? Wq : (proj == 1) ? Wk : Wv;
  const float* bias = (proj == 0) ? bq : (proj == 1) ? bk : bv;
  unsigned short* Out = (proj == 0) ? Qh : (proj == 1) ? Kh : Vt;
  const float oscale = (proj == 0) ? qscale : 1.0f;

  const int wr   = (w >> 1) * 32;     // 0 or 32
  const int wc   = (w & 1) * 64;      // 0 or 64
  const int base = w * 1024 + lane * 16;

  auto stage = [&](int buf, int k0) {   // exactly 4 stage16 per thread
    char* sA = smem + buf * 16384;
    char* sB = sA + 8192;
    #pragma unroll
    for (int c = 0; c < 2; ++c) {       // A: 8 KB f32 [64 rows][8 granules of 4 f32]
      const int flat = c * 4096 + base;
      const int row  = flat >> 7;
      const int gl   = ((flat >> 4) & 7) ^ (row & 7);
      stage16(&A[(size_t)(m0 + row) * K + k0 + gl * 4], sA + flat);
    }
    #pragma unroll
    for (int c = 0; c < 2; ++c) {       // B: 8 KB bf16, 128 n-rows x 32 cols
      const int flat = c * 4096 + base;
      const int r    = flat >> 7;
      const int gl   = ((flat >> 4) & 7) ^ (r & 7);
      const int nn   = r + ((gl >> 2) << 6);
      stage16(&Bw[(size_t)(n0 + nn) * K + k0 + (gl & 3) * 8], sB + flat);
    }
  };

  f32x4 acc[2][4] = {};
  auto compute = [&](int buf) {
    char* sA = smem + buf * 16384;
    char* sB = sA + 8192;
    s16x8 af[2], bf[4];
    #pragma unroll
    for (int i = 0; i < 2; ++i) {
      const int row = wr + i * 16 + (lane & 15);
      const int g1  = (lane >> 4) << 1;
      float4 v1 = *reinterpret_cast<const float4*>(sA + row * 128 + ((g1 ^ (row & 7)) << 4));
      float4 v2 = *reinterpret_cast<const float4*>(sA + row * 128 + (((g1 + 1) ^ (row & 7)) << 4));
      union { ushort4 p[2]; s16x8 vv; } cc;
      cc.p[0] = pack4bf(v1); cc.p[1] = pack4bf(v2);
      af[i] = cc.vv;
    }
    #pragma unroll
    for (int jj = 0; jj < 4; ++jj) {
      const int n  = wc + jj * 16 + (lane & 15);
      const int r  = n & 63;
      const int gl = ((n >> 6) << 2) + (lane >> 4);
      bf[jj] = *reinterpret_cast<const s16x8*>(sB + r * 128 + ((gl ^ (r & 7)) << 4));
    }
    __builtin_amdgcn_s_setprio(1);
    #pragma unroll
    for (int i = 0; i < 2; ++i)
      #pragma unroll
      for (int jj = 0; jj < 4; ++jj)
        acc[i][jj] = __builtin_amdgcn_mfma_f32_16x16x32_bf16(af[i], bf[jj], acc[i][jj], 0, 0, 0);
    __builtin_amdgcn_s_setprio(0);
  };

  stage(0, 0);
  int cur = 0;
  for (int t = 0; t < 15; ++t) {
    stage(cur ^ 1, (t + 1) * 32);       // stays in flight across the barrier
    asm volatile("s_waitcnt vmcnt(4)" ::: "memory");   // tile t landed
    __builtin_amdgcn_s_barrier();
    __builtin_amdgcn_sched_barrier(0);
    compute(cur);
    asm volatile("s_waitcnt lgkmcnt(0)" ::: "memory"); // ds_reads done
    __builtin_amdgcn_s_barrier();
    cur ^= 1;
  }
  asm volatile("s_waitcnt vmcnt(0)" ::: "memory");
  __builtin_amdgcn_s_barrier();
  __builtin_amdgcn_sched_barrier(0);
  compute(cur);
  __syncthreads();                      // smem reused by epilogue tile

  // ---- epilogue: bf16 tile through LDS, then coalesced 16B stores ----
  // proj 0/1: tile [64 m][256 B of n];  proj 2: tile [128 n][128 B of m].
  char* const tl = smem;
  #pragma unroll
  for (int jj = 0; jj < 4; ++jj) {
    const int n  = wc + jj * 16 + (lane & 15);
    const float bs = bias[n0 + n];
    #pragma unroll
    for (int i = 0; i < 2; ++i)
      #pragma unroll
      for (int r = 0; r < 4; ++r) {
        const int m = wr + i * 16 + (lane >> 4) * 4 + r;
        const unsigned short val = f2bf((acc[i][jj][r] + bs) * oscale);
        if (proj == 2)
          *(unsigned short*)(tl + n * 128 + ((m * 2) ^ ((n & 7) << 4))) = val;
        else
          *(unsigned short*)(tl + m * 256 + ((n * 2) ^ ((m & 7) << 4))) = val;
      }
  }
  __syncthreads();
  #pragma unroll
  for (int c = 0; c < 4; ++c) {
    const int flat = c * 4096 + tid * 16;
    size_t dst;
    s16x8 vchunk;
    if (proj == 2) {
      const int rowi = flat >> 7;           // n: 0..127
      const int cb   = flat & 127;          // m-bytes
      vchunk = *reinterpret_cast<const s16x8*>(tl + rowi * 128 + (cb ^ ((rowi & 7) << 4)));
      const int gn = n0 + rowi;
      const int b  = m0 >> 9, sb = (m0 & 511) + (cb >> 1);
      const int h  = gn >> 6, d = gn & 63;
      dst = ((size_t)(b * NH + h) * DKD + d) * SEQ + sb;
    } else {
      const int rowi = flat >> 8;           // m: 0..63
      const int cb   = flat & 255;          // n-bytes
      vchunk = *reinterpret_cast<const s16x8*>(tl + rowi * 256 + (cb ^ ((rowi & 7) << 4)));
      const int gm = m0 + rowi;
      const int gn = n0 + (cb >> 1);
      const int b  = gm >> 9, s = gm & 511;
      const int h  = gn >> 6, d = gn & 63;
      dst = ((size_t)(b * NH + h) * SEQ + s) * DKD + d;
    }
    *reinterpret_cast<s16x8*>(&Out[dst]) = vchunk;
  }
}

// ===================== output GEMM (At bf16 @ Wo^T + bo -> f32) ============
// Grid 512 1-D, XCD-pinned (P = x*16 + (j>>2): b in [4x,4x+4) matches attn's
// producer XCD). Counted-vmcnt dbuf pipeline; 4 loads/thread -> vmcnt(4).
__global__ __launch_bounds__(256)
void out_gemm(const unsigned short* __restrict__ At,
              const unsigned short* __restrict__ Wo,
              const float* __restrict__ bo, float* __restrict__ C)
{
  __shared__ __align__(16) char smem[2 * 16384];
  const int tid  = threadIdx.x;
  const int lane = tid & 63;
  const int w    = tid >> 6;
  const int lin  = blockIdx.x;
  const int x    = lin & 7;
  const int j    = lin >> 3;
  const int P    = x * 16 + (j >> 2);
  const int m0   = P * 128;
  const int n0   = (j & 3) * 128;
  const int K = EMB, N = EMB;

  const int wr   = (w >> 1) * 64;
  const int wc   = (w & 1) * 64;
  const int base = w * 1024 + lane * 16;

  auto stage = [&](int buf, int k0) {   // exactly 4 global_load_lds per thread
    char* sA = smem + buf * 16384;
    char* sB = sA + 8192;
    #pragma unroll
    for (int c = 0; c < 2; ++c) {
      const int flat = c * 4096 + base;
      const int r    = flat >> 7;
      const int gl   = ((flat >> 4) & 7) ^ (r & 7);
      const int row  = r + ((gl >> 2) << 6);
      stage16(&At[(size_t)(m0 + row) * K + k0 + (gl & 3) * 8], sA + flat);
    }
    #pragma unroll
    for (int c = 0; c < 2; ++c) {
      const int flat = c * 4096 + base;
      const int r    = flat >> 7;
      const int gl   = ((flat >> 4) & 7) ^ (r & 7);
      const int nn   = r + ((gl >> 2) << 6);
      stage16(&Wo[(size_t)(n0 + nn) * K + k0 + (gl & 3) * 8], sB + flat);
    }
  };

  f32x4 acc[4][4] = {};
  auto compute = [&](int buf) {
    char* sA = smem + buf * 16384;
    char* sB = sA + 8192;
    s16x8 af[4], bf[4];
    #pragma unroll
    for (int i = 0; i < 4; ++i) {
      const int row = wr + i * 16 + (lane & 15);
      const int r   = row & 63;
      const int gl  = ((row >> 6) << 2) + (lane >> 4);
      af[i] = *reinterpret_cast<const s16x8*>(sA + r * 128 + ((gl ^ (r & 7)) << 4));
    }
    #pragma unroll
    for (int jj = 0; jj < 4; ++jj) {
      const int n  = wc + jj * 16 + (lane & 15);
      const int r  = n & 63;
      const int gl = ((n >> 6) << 2) + (lane >> 4);
      bf[jj] = *reinterpret_cast<const s16x8*>(sB + r * 128 + ((gl ^ (r & 7)) << 4));
    }
    __builtin_amdgcn_s_setprio(1);
    #pragma unroll
    for (int i = 0; i < 4; ++i)
      #pragma unroll
      for (int jj = 0; jj < 4; ++jj)
        acc[i][jj] = __builtin_amdgcn_mfma_f32_16x16x32_bf16(af[i], bf[jj], acc[i][jj], 0, 0, 0);
    __builtin_amdgcn_s_setprio(0);
  };

  stage(0, 0);
  int cur = 0;
  for (int t = 0; t < 15; ++t) {
    stage(cur ^ 1, (t + 1) * 32);
    asm volatile("s_waitcnt vmcnt(4)" ::: "memory");
    __builtin_amdgcn_s_barrier();
    __builtin_amdgcn_sched_barrier(0);
    compute(cur);
    asm volatile("s_waitcnt lgkmcnt(0)" ::: "memory");
    __builtin_amdgcn_s_barrier();
    cur ^= 1;
  }
  asm volatile("s_waitcnt vmcnt(0)" ::: "memory");
  __builtin_amdgcn_s_barrier();
  __builtin_amdgcn_sched_barrier(0);
  compute(cur);

  #pragma unroll
  for (int i = 0; i < 4; ++i)
    #pragma unroll
    for (int jj = 0; jj < 4; ++jj)
      #pragma unroll
      for (int r = 0; r < 4; ++r) {
        const int gm = m0 + wr + i * 16 + (lane >> 4) * 4 + r;
        const int gn = n0 + wc + jj * 16 + (lane & 15);
        C[(size_t)gm * N + gn] = acc[i][jj][r] + bo[gn];
      }
}

// ---- phase 2 worker: R rows per iteration, 64/R lanes per row segment.
// DPP row_shr scans are naturally segmented at 16-lane boundaries.
template<int R>
__device__ inline void phase2_rows(unsigned short* s_lds, int w, int lane,
                                   int q0, int zp, float g2)
{
  constexpr int L  = 64 / R;   // lanes per segment
  constexpr int IT = 4 / R;    // iterations
  const int seg = lane / L;
  const int li  = lane & (L - 1);
  const int jb  = li * 8;
  const float NEGINF = -__builtin_inff();
  #pragma unroll
  for (int it = 0; it < IT; ++it) {
    const int r  = w * 4 + it * R + seg;
    const int qg = q0 + r;
    const int gs = li ^ (r & 7);
    unsigned short* rowp = &s_lds[r * 512 + gs * 8];
    float pn2[8];
    if (qg == 0) {
      const float u = zp ? 0.0f : (1.0f / 512.0f);
      #pragma unroll
      for (int i = 0; i < 8; ++i) pn2[i] = u;
    } else {
      float sL[8];
      {
        s16x8 raw = *reinterpret_cast<const s16x8*>(rowp);
        union { s16x8 v; __half2 h[4]; } u; u.v = raw;
        #pragma unroll
        for (int i = 0; i < 4; ++i) {
          float2 f = __half22float2(u.h[i]);
          sL[2 * i] = f.x; sL[2 * i + 1] = f.y;
        }
      }
      #pragma unroll
      for (int i = 0; i < 8; ++i) sL[i] = (jb + i < qg) ? sL[i] : NEGINF;
      float p[8], c[8];
      float run = 0.f;
      #pragma unroll
      for (int i = 0; i < 8; ++i) { p[i] = EXP2(sL[i]); run += p[i]; c[i] = run; }
      // segmented inclusive scan of per-lane totals
      float t = run;
      t += dpp_shr_f<0x111>(t);
      t += dpp_shr_f<0x112>(t);
      t += dpp_shr_f<0x114>(t);
      t += dpp_shr_f<0x118>(t);
      float tot;
      if constexpr (R == 1) {
        const float r0 = rlane(t, 15), r1 = rlane(t, 31), r2 = rlane(t, 47);
        const float a1 = r0, a2 = r0 + r1, a3 = a2 + r2;
        tot = a3 + rlane(t, 63);
        t += (lane >= 48) ? a3 : (lane >= 32) ? a2 : (lane >= 16) ? a1 : 0.f;
      } else if constexpr (R == 2) {
        const float r0 = rlane(t, 15), r2 = rlane(t, 47);
        t += (lane & 16) ? ((lane < 32) ? r0 : r2) : 0.f;
        tot = __shfl(t, lane | 31, 64);
      } else {
        tot = __shfl(t, lane | 15, 64);
      }
      const float pre  = tot - (t - run);     // tot - exclusive_prefix(lane)
      const float g2r  = g2 * __builtin_amdgcn_sqrtf(RCP(tot));
      const float fb   = (float)(qg - jb);
      float p2[8]; float run2 = 0.f;
      #pragma unroll
      for (int i = 0; i < 8; ++i) {
        const float rem = pre - c[i];
        const float arg = fmaxf(rem * (fb - (float)i), 0.f);
        float te = EXP2(__builtin_amdgcn_sqrtf(arg) * g2r);
        te = fmaxf(te, 1e-5f);
        p2[i] = EXP2(sL[i] * te);
        run2 += p2[i];
      }
      float y = run2;
      y += dpp_shr_f<0x111>(y);
      y += dpp_shr_f<0x112>(y);
      y += dpp_shr_f<0x114>(y);
      y += dpp_shr_f<0x118>(y);
      float s2;
      if constexpr (R == 1) {
        s2 = rlane(y, 15) + rlane(y, 31) + rlane(y, 47) + rlane(y, 63);
      } else if constexpr (R == 2) {
        y += (lane & 16) ? ((lane < 32) ? rlane(y, 15) : rlane(y, 47)) : 0.f;
        s2 = __shfl(y, lane | 31, 64);
      } else {
        s2 = __shfl(y, lane | 15, 64);
      }
      const float inv2 = RCP(s2);
      #pragma unroll
      for (int i = 0; i < 8; ++i) pn2[i] = p2[i] * inv2;
    }
    union { __hip_bfloat162 h2[4]; uint4 u; } pk;
    pk.h2[0] = __float22bfloat162_rn(make_float2(pn2[0], pn2[1]));
    pk.h2[1] = __float22bfloat162_rn(make_float2(pn2[2], pn2[3]));
    pk.h2[2] = __float22bfloat162_rn(make_float2(pn2[4], pn2[5]));
    pk.h2[3] = __float22bfloat162_rn(make_float2(pn2[6], pn2[7]));
    *reinterpret_cast<uint4*>(rowp) = pk.u;
  }
}

// One WG (4 waves) per (b, h, 16-row q-block). Grid 8192 1-D.
// Work decode puts qb in the HIGH bits of the per-XCD index: under round-robin
// dispatch (xcd = lin%8, CU = (lin/8)%32), CU c of xcd x receives u = c + 32j,
// j=0..31  ->  (b,h) = f(c,x) CONSTANT per CU (K/V/Q pinned in its L1/L2) while
// qb = j sweeps 0..31 (identical total work per CU, dynamic drain over 32 WGs).
// LDS: 16 KB. Scores f16, row-major [16][512], granule-swizzled:
//   col n of row -> ushort idx  row*512 + (((n>>3) ^ (row&7))<<3) + (n&7)
// bf16 P overlays the same slots. Triangular trims throughout. Out: bf16.
__global__ __launch_bounds__(256)
void attn_kernel(const unsigned short* __restrict__ Qh,
                 const unsigned short* __restrict__ Kh,
                 const unsigned short* __restrict__ Vt,
                 unsigned short* __restrict__ Aout,
                 const float* __restrict__ gammas,
                 const int* __restrict__ zero_pad)
{
  __shared__ __align__(16) unsigned short s_lds[16 * 512];   // 16 KB
  const int tid = threadIdx.x, lane = tid & 63, w = tid >> 6;
  const int lin = blockIdx.x;
  const int x   = lin & 7;          // xcd
  const int u   = lin >> 3;         // 0..1023 within xcd
  const int qb  = u >> 5;           // 0..31  (high bits -> varies per CU)
  const int h   = u & 7;
  const int b   = x * 4 + ((u >> 3) & 3);
  const int q0  = qb * 16;
  const size_t bh = (size_t)b * NH + h;
  const unsigned short* Qp = Qh + bh * SEQ * DKD;
  const unsigned short* Kp = Kh + bh * SEQ * DKD;
  const unsigned short* Vp = Vt + bh * DKD * SEQ;
  const int zp = zero_pad[0];
  const float g2 = -log1pf(__expf(gammas[h])) * LOG2E;  // -softplus(g) * log2(e)

  // ---- phase 1: S(log2-domain) = Qs @ K^T (Q pre-scaled by log2e/8), f16 to LDS.
  // 16-col MFMA tile t (t <= qb needed) -> wave (t & 3): balanced; 2-deep prefetch.
  s16x8 aq[2];
  #pragma unroll
  for (int kt = 0; kt < 2; ++kt)
    aq[kt] = *reinterpret_cast<const s16x8*>(&Qp[(q0 + (lane & 15)) * DKD + kt * 32 + (lane >> 4) * 8]);
  {
    const int frag = (lane >> 4) * 8;
    auto loadK = [&](int t, s16x8* kb) {
      const int n = t * 16 + (lane & 15);
      kb[0] = *reinterpret_cast<const s16x8*>(&Kp[n * DKD + frag]);
      kb[1] = *reinterpret_cast<const s16x8*>(&Kp[n * DKD + 32 + frag]);
    };
    auto tilecomp = [&](int t, const s16x8* kb) {
      f32x4 acc = {};
      __builtin_amdgcn_s_setprio(1);
      acc = __builtin_amdgcn_mfma_f32_16x16x32_bf16(aq[0], kb[0], acc, 0, 0, 0);
      acc = __builtin_amdgcn_mfma_f32_16x16x32_bf16(aq[1], kb[1], acc, 0, 0, 0);
      __builtin_amdgcn_s_setprio(0);
      const int n = t * 16 + (lane & 15);
      #pragma unroll
      for (int r = 0; r < 4; ++r) {
        const int row = (lane >> 4) * 4 + r;
        const int idx = row * 512 + ((((n >> 3) ^ (row & 7)) << 3) + (n & 7));
        s_lds[idx] = __half_as_ushort(__float2half(acc[r]));
      }
    };
    int t = w;
    if (t <= qb) {
      s16x8 cur[2], nxt[2];
      loadK(t, cur);
      while (true) {
        const int tn = t + 4;
        if (tn <= qb) {
          loadK(tn, nxt);
          tilecomp(t, cur);
          cur[0] = nxt[0]; cur[1] = nxt[1];
          t = tn;
        } else {
          tilecomp(t, cur);
          break;
        }
      }
    }
  }
  __syncthreads();

  // ---- phase 2: softmax -> cumsum -> decay -> softmax2 -> bf16 P (overlaid)
  if (zp == 0 && qb == 0) {
    phase2_rows<1>(s_lds, w, lane, q0, zp, g2);   // row 0 spans all 512 cols
  } else if (qb < 8) {
    phase2_rows<4>(s_lds, w, lane, q0, zp, g2);
  } else if (qb < 16) {
    phase2_rows<2>(s_lds, w, lane, q0, zp, g2);
  } else {
    phase2_rows<1>(s_lds, w, lane, q0, zp, g2);
  }
  __syncthreads();

  // ---- phase 3: out = P @ V (V stored [d][s]); wave w -> d cols [w*16, w*16+16)
  // k-tile ks needed iff ks <= qb/2. Batch-4 loads to break the latency chain.
  f32x4 oacc = {};
  const int row  = lane & 15;
  const int koff = lane >> 4;
  const int rsw  = row & 7;
  const unsigned short* vbase = &Vp[(w * 16 + row) * SEQ + koff * 8];
  const int ks_end = (qb == 0 && zp == 0) ? 16 : (qb >> 1) + 1;
  int ks0 = 0;
  for (; ks0 + 4 <= ks_end; ks0 += 4) {
    s16x8 vb[4], pa[4];
    #pragma unroll
    for (int uu = 0; uu < 4; ++uu) {
      const int ks = ks0 + uu;
      vb[uu] = *reinterpret_cast<const s16x8*>(&vbase[ks * 32]);
      pa[uu] = *reinterpret_cast<const s16x8*>(&s_lds[row * 512 + ((ks * 4 + koff) ^ rsw) * 8]);
    }
    __builtin_amdgcn_s_setprio(1);
    #pragma unroll
    for (int uu = 0; uu < 4; ++uu)
      oacc = __builtin_amdgcn_mfma_f32_16x16x32_bf16(pa[uu], vb[uu], oacc, 0, 0, 0);
    __builtin_amdgcn_s_setprio(0);
  }
  for (; ks0 < ks_end; ++ks0) {
    s16x8 vb = *reinterpret_cast<const s16x8*>(&vbase[ks0 * 32]);
    s16x8 pa = *reinterpret_cast<const s16x8*>(&s_lds[row * 512 + ((ks0 * 4 + koff) ^ rsw) * 8]);
    oacc = __builtin_amdgcn_mfma_f32_16x16x32_bf16(pa, vb, oacc, 0, 0, 0);
  }
  #pragma unroll
  for (int r = 0; r < 4; ++r) {
    const int orow = (lane >> 4) * 4 + r;
    const int ocol = w * 16 + (lane & 15);
    Aout[((size_t)b * SEQ + (q0 + orow)) * EMB + h * DKD + ocol] = f2bf(oacc[r]);
  }
}

extern "C" void kernel_launch(void* const* d_in, const int* in_sizes, int n_in,
                              void* d_out, int out_size, void* d_ws, size_t ws_size,
                              hipStream_t stream)
{
  const float* q  = (const float*)d_in[0];
  const float* k  = (const float*)d_in[1];
  const float* v  = (const float*)d_in[2];
  // d_in[3] = mask (strictly causal, computed analytically on device)
  const int*   zp = (const int*)d_in[4];
  const float* Wq = (const float*)d_in[5];
  const float* bq = (const float*)d_in[6];
  const float* Wk = (const float*)d_in[7];
  const float* bk = (const float*)d_in[8];
  const float* Wv = (const float*)d_in[9];
  const float* bv = (const float*)d_in[10];
  const float* Wo = (const float*)d_in[11];
  const float* bo = (const float*)d_in[12];
  const float* gm = (const float*)d_in[13];

  char* ws = (char*)d_ws;
  const size_t HB = (size_t)BSZ * NH * SEQ * DKD * sizeof(unsigned short); // 16 MiB
  const size_t WB = (size_t)EMB * EMB * sizeof(unsigned short);            // 512 KiB
  unsigned short* Qh  = (unsigned short*)(ws);
  unsigned short* Kh  = (unsigned short*)(ws + HB);
  unsigned short* Vt  = (unsigned short*)(ws + 2 * HB);
  unsigned short* At  = (unsigned short*)(ws + 3 * HB);   // bf16 attn output
  unsigned short* Wqb = (unsigned short*)(ws + 4 * HB);
  unsigned short* Wkb = (unsigned short*)(ws + 4 * HB + WB);
  unsigned short* Wvb = (unsigned short*)(ws + 4 * HB + 2 * WB);
  unsigned short* Wob = (unsigned short*)(ws + 4 * HB + 3 * WB);

  wcvt<<<dim3(128, 4), 256, 0, stream>>>(Wq, Wk, Wv, Wo, Wqb, Wkb, Wvb, Wob);
  proj_gemm<<<3072, 256, 0, stream>>>(q, k, v, Wqb, Wkb, Wvb, bq, bk, bv,
                                      Qh, Kh, Vt, 0.125f * LOG2E);
  attn_kernel<<<8192, 256, 0, stream>>>(Qh, Kh, Vt, At, gm, zp);
  out_gemm<<<512, 256, 0, stream>>>(At, Wob, bo, (float*)d_out);
}